// Round 3
// baseline (26.920 us; speedup 1.0000x reference)
//
#include <hip/hip_runtime.h>

namespace {
constexpr int B_ = 4;
constexpr int N_ = 240 * 320;     // 76800 pixels per image (C == 1)
constexpr int M_ = 256;           // bins
constexpr int PIX = 512;          // pixels per main block
constexpr int CHUNKS = N_ / PIX;  // 150 blocks per batch
constexpr int NBLK = B_ * CHUNKS; // 600 main blocks

// ws layout (float words). Every slot is written unconditionally each call
// (no init kernel, no atomics, deterministic).
constexpr int WS_BINPART = 0;                  // [NBLK][M_]  per-block bin mins (raw)
constexpr int WS_MAXPART = NBLK * M_;          // [NBLK]      per-block pixel max
constexpr int WS_T2BPART = WS_MAXPART + NBLK;  // [NBLK]      per-block t2b sums (raw)
constexpr int WS_BINMIN  = WS_T2BPART + NBLK;  // [B_][M_]    per-batch bin mins (raw)
}  // namespace

// Main pass on RAW (unnormalized) values: (c/m - t/m)^2 == (c-t)^2 / m^2, so
// normalization is deferred to the final kernel (scale by 1/m^2 per batch).
__global__ __launch_bounds__(512) void chamfer_main_kernel(const float* __restrict__ target,
                                                           const float* __restrict__ bins,
                                                           float* __restrict__ ws) {
  const int bid = blockIdx.x;
  const int b = bid / CHUNKS;
  const int chunk = bid - b * CHUNKS;
  const int tid = threadIdx.x;

  __shared__ __align__(16) float lds_bins[M_];
  __shared__ __align__(16) float lds_t[PIX];
  __shared__ float lds_red[PIX];
  __shared__ float lds_sum[8];
  __shared__ float lds_max[8];

  if (tid < M_) lds_bins[tid] = bins[b * M_ + tid];
  const float t_i = target[b * N_ + chunk * PIX + tid];
  lds_t[tid] = t_i;

  // per-wave max of staged pixels (feeds per-batch max reduction)
  float mx = t_i;
#pragma unroll
  for (int o = 32; o > 0; o >>= 1) mx = fmaxf(mx, __shfl_down(mx, o));
  if ((tid & 63) == 0) lds_max[tid >> 6] = mx;

  __syncthreads();

  // ---- Phase A: thread = pixel; min over 256 bins (LDS broadcast reads) ----
  const float4* bins4 = reinterpret_cast<const float4*>(lds_bins);
  float a0 = 3.4e38f, a1 = 3.4e38f;  // two accumulators for ILP
#pragma unroll 8
  for (int m4 = 0; m4 < M_ / 4; m4 += 2) {
    float4 c0 = bins4[m4];
    float4 c1 = bins4[m4 + 1];
    float d0 = c0.x - t_i; d0 *= d0;
    float d1 = c0.y - t_i; d1 *= d1;
    float d2 = c0.z - t_i; d2 *= d2;
    float d3 = c0.w - t_i; d3 *= d3;
    float x = fminf(fminf(d0, d1), d2);   // v_min3
    a0 = fminf(fminf(x, d3), a0);         // v_min3
    float e0 = c1.x - t_i; e0 *= e0;
    float e1 = c1.y - t_i; e1 *= e1;
    float e2 = c1.z - t_i; e2 *= e2;
    float e3 = c1.w - t_i; e3 *= e3;
    float y = fminf(fminf(e0, e1), e2);
    a1 = fminf(fminf(y, e3), a1);
  }
  const float tmin = fminf(a0, a1);

  // ---- Phase B: thread (q = tid>>8, j = tid&255) = bin j over half-tile q ----
  const int j = tid & 255;
  const float c_j = lds_bins[j];
  const float4* t4 = reinterpret_cast<const float4*>(lds_t + (tid >> 8) * 256);
  float b0 = 3.4e38f, b1 = 3.4e38f;
#pragma unroll 8
  for (int p4 = 0; p4 < 64; p4 += 2) {
    float4 u0 = t4[p4];
    float4 u1 = t4[p4 + 1];
    float d0 = c_j - u0.x; d0 *= d0;
    float d1 = c_j - u0.y; d1 *= d1;
    float d2 = c_j - u0.z; d2 *= d2;
    float d3 = c_j - u0.w; d3 *= d3;
    float x = fminf(fminf(d0, d1), d2);
    b0 = fminf(fminf(x, d3), b0);
    float e0 = c_j - u1.x; e0 *= e0;
    float e1 = c_j - u1.y; e1 *= e1;
    float e2 = c_j - u1.z; e2 *= e2;
    float e3 = c_j - u1.w; e3 *= e3;
    float y = fminf(fminf(e0, e1), e2);
    b1 = fminf(fminf(y, e3), b1);
  }
  const float binmin = fminf(b0, b1);

  // ---- Reductions (fixed order -> deterministic) ----
  float s = tmin;
#pragma unroll
  for (int o = 32; o > 0; o >>= 1) s += __shfl_down(s, o);
  if ((tid & 63) == 0) lds_sum[tid >> 6] = s;
  lds_red[tid] = binmin;
  __syncthreads();

  if (tid == 0) {
    float tot = lds_sum[0], mm = lds_max[0];
#pragma unroll
    for (int w = 1; w < 8; ++w) {
      tot += lds_sum[w];
      mm = fmaxf(mm, lds_max[w]);
    }
    ws[WS_T2BPART + bid] = tot;
    ws[WS_MAXPART + bid] = mm;
  }
  if (tid < M_) {
    ws[WS_BINPART + bid * M_ + tid] = fminf(lds_red[tid], lds_red[256 + tid]);
  }
}

// Min over the 150 chunk-partials per (batch, bin). 16 blocks x 256 threads.
__global__ void reduce_bins_kernel(float* __restrict__ ws) {
  const int b = blockIdx.x >> 2;
  const int slice = blockIdx.x & 3;            // which 64-bin slice
  const int jo = threadIdx.x & 63;
  const int kk = threadIdx.x >> 6;             // 0..3 chunk-stripe
  const int j = slice * 64 + jo;
  float v = 3.4e38f;
  for (int k = kk; k < CHUNKS; k += 4)
    v = fminf(v, ws[WS_BINPART + (b * CHUNKS + k) * M_ + j]);
  __shared__ float lds[256];
  lds[threadIdx.x] = v;
  __syncthreads();
  if (threadIdx.x < 64) {
    float r = fminf(fminf(lds[threadIdx.x], lds[64 + threadIdx.x]),
                    fminf(lds[128 + threadIdx.x], lds[192 + threadIdx.x]));
    ws[WS_BINMIN + b * M_ + slice * 64 + threadIdx.x] = r;
  }
}

__global__ __launch_bounds__(1024) void chamfer_final_kernel(const float* __restrict__ ws,
                                                             float* __restrict__ out) {
  const int tid = threadIdx.x;
  const int b = tid >> 8;
  const int t = tid & 255;

  float mx = (t < CHUNKS) ? ws[WS_MAXPART + b * CHUNKS + t] : 0.f;
  float sb = ws[WS_BINMIN + b * M_ + t];
  float st = (t < CHUNKS) ? ws[WS_T2BPART + b * CHUNKS + t] : 0.f;
#pragma unroll
  for (int o = 32; o > 0; o >>= 1) {
    mx = fmaxf(mx, __shfl_down(mx, o));
    sb += __shfl_down(sb, o);
    st += __shfl_down(st, o);
  }
  __shared__ float lmax[16], lsb[16], lst[16];
  if ((tid & 63) == 0) {
    const int w = tid >> 6;
    lmax[w] = mx; lsb[w] = sb; lst[w] = st;
  }
  __syncthreads();
  if (tid == 0) {
    float loss = 0.f;
#pragma unroll
    for (int bb = 0; bb < B_; ++bb) {
      float m2 = 0.f, s1 = 0.f, s2 = 0.f;
#pragma unroll
      for (int w = 0; w < 4; ++w) {
        m2 = fmaxf(m2, lmax[bb * 4 + w]);
        s1 += lsb[bb * 4 + w];
        s2 += lst[bb * 4 + w];
      }
      const float inv = 1.0f / (m2 * m2);  // deferred normalization
      loss += (s1 / (float)M_) * inv + (s2 / (float)N_) * inv;
    }
    out[0] = loss / (float)B_ * 10.0f;
  }
}

extern "C" void kernel_launch(void* const* d_in, const int* in_sizes, int n_in,
                              void* d_out, int out_size, void* d_ws, size_t ws_size,
                              hipStream_t stream) {
  (void)in_sizes; (void)n_in; (void)out_size; (void)ws_size;
  const float* target = reinterpret_cast<const float*>(d_in[0]);
  const float* bins = reinterpret_cast<const float*>(d_in[1]);
  float* ws = reinterpret_cast<float*>(d_ws);
  float* out = reinterpret_cast<float*>(d_out);

  chamfer_main_kernel<<<NBLK, 512, 0, stream>>>(target, bins, ws);
  reduce_bins_kernel<<<16, 256, 0, stream>>>(ws);
  chamfer_final_kernel<<<1, 1024, 0, stream>>>(ws, out);
}